// Round 12
// baseline (171.507 us; speedup 1.0000x reference)
//
#include <hip/hip_runtime.h>

// InverseConsistencyLoss — round 12: 12B fp8 corner-quad entries.
//  * repack v3: 4 entries/thread, float4 reads, LDS-staged DENSE dwordx4 writes
//  * main: persistent 2048 blocks x 4 tiles (8 blocks/CU resident), 2 barriers
//    per tile, accumulate across tiles.
// Entry(z,y,x) = {c0,c1,c2} at (z,y),(z,y1),(z1,y),(z1,y1), clamps baked, 12 B.
// Main: dwordx4 + dwordx2 at byte 12*idx span 24 contiguous bytes = both
// x-corners' entries = all 8 trilinear corners, ~1.2 L2-line-visits/pos.
// Sample semantics: output voxel (d,h,w) samples V at
// (z=clip(w+a2), y=clip(h+a1), x=clip(d+a0)), x fastest; lane==d.

#define CS    2097152          // 128^3
#define BS    (3*CS)
#define NTHR  256
#define NBLK_MAIN 2048         // 8 XCDs * 256 persistent blocks
#define EB    12               // entry bytes
#define INV_N (1.0f/12582912.0f)

#if defined(__has_builtin)
#if __has_builtin(__builtin_amdgcn_cvt_pk_fp8_f32) && __has_builtin(__builtin_amdgcn_cvt_pk_f32_fp8)
#define HW_FP8 1
#endif
#endif

typedef float v2f __attribute__((ext_vector_type(2)));
struct __attribute__((aligned(4))) U4a4 { unsigned x, y, z, w; };
struct __attribute__((aligned(4))) U2a4 { unsigned x, y; };

// ---------- manual OCP e4m3fn fallback (self-consistent) ----------
__device__ __forceinline__ unsigned enc1_sw(float x) {
    union { float f; unsigned u; } v; v.f = x;
    unsigned s = v.u >> 31;
    float ax = fminf(fabsf(x), 448.0f);
    if (ax < 0.015625f) return s << 7;
    v.f = ax;
    unsigned u = v.u;
    u += 0x7FFFF + ((u >> 20) & 1);
    unsigned e = (u >> 23) - 120;
    if (e > 15) { e = 15; u = 0x7u << 20; }
    return (s << 7) | (e << 3) | ((u >> 20) & 7);
}
__device__ __forceinline__ float dec1_sw(unsigned b) {
    unsigned s = b >> 7, e = (b >> 3) & 15, m = b & 7;
    union { unsigned u; float f; } v;
    if (e == 0) { float r = (float)m * 0.001953125f; return s ? -r : r; }
    v.u = (s << 31) | ((e + 120) << 23) | (m << 20);
    return v.f;
}
template <bool HI>
__device__ __forceinline__ unsigned enc_pk(float a, float b, unsigned old) {
#ifdef HW_FP8
    return (unsigned)__builtin_amdgcn_cvt_pk_fp8_f32(a, b, (int)old, HI);
#else
    unsigned p = enc1_sw(a) | (enc1_sw(b) << 8);
    return HI ? ((old & 0x0000FFFFu) | (p << 16)) : ((old & 0xFFFF0000u) | p);
#endif
}
template <bool HI>
__device__ __forceinline__ v2f dec_pk(unsigned u) {
#ifdef HW_FP8
    return __builtin_amdgcn_cvt_pk_f32_fp8((int)u, HI);
#else
    unsigned p = HI ? (u >> 16) : u;
    v2f r; r.x = dec1_sw(p & 255); r.y = dec1_sw((p >> 8) & 255);
    return r;
#endif
}

// ---------- repack v3: 4 entries/thread, float4 reads, dense LDS-staged writes
// grid 8192 x 256; thread = x-quad of entries (48 B of output).
__global__ __launch_bounds__(NTHR)
void repack12(const float* __restrict__ F, const float* __restrict__ G,
              uint4* __restrict__ P4) {
    __shared__ uint4 sL[3 * NTHR];                  // 12 KB
    unsigned g = blockIdx.x * NTHR + threadIdx.x;   // 0 .. 2^21-1
    int x = (g & 31) << 2;
    int y = (g >> 5) & 127;
    int z = (g >> 12) & 127;
    int b = (g >> 19) & 1;
    int field = (g >> 20) & 1;
    const float* src = (field ? G : F) + b * BS;
    int y1 = min(y + 1, 127), z1 = min(z + 1, 127);
    int iA = (z << 14) + (y << 7) + x;    // (z,y)
    int iB = (z << 14) + (y1 << 7) + x;   // (z,y1)
    int iC = (z1 << 14) + (y << 7) + x;   // (z1,y)
    int iD = (z1 << 14) + (y1 << 7) + x;  // (z1,y1)
    float4 A0 = *(const float4*)(src + iA);
    float4 A1 = *(const float4*)(src + CS + iA);
    float4 A2 = *(const float4*)(src + 2 * CS + iA);
    float4 B0 = *(const float4*)(src + iB);
    float4 B1 = *(const float4*)(src + CS + iB);
    float4 B2 = *(const float4*)(src + 2 * CS + iB);
    float4 C0 = *(const float4*)(src + iC);
    float4 C1 = *(const float4*)(src + CS + iC);
    float4 C2 = *(const float4*)(src + 2 * CS + iC);
    float4 D0 = *(const float4*)(src + iD);
    float4 D1 = *(const float4*)(src + CS + iD);
    float4 D2 = *(const float4*)(src + 2 * CS + iD);
    const float* pA0 = (const float*)&A0; const float* pA1 = (const float*)&A1;
    const float* pA2 = (const float*)&A2; const float* pB0 = (const float*)&B0;
    const float* pB1 = (const float*)&B1; const float* pB2 = (const float*)&B2;
    const float* pC0 = (const float*)&C0; const float* pC1 = (const float*)&C1;
    const float* pC2 = (const float*)&C2; const float* pD0 = (const float*)&D0;
    const float* pD1 = (const float*)&D1; const float* pD2 = (const float*)&D2;
    unsigned wrd[12];
    #pragma unroll
    for (int k = 0; k < 4; ++k) {
        // words: w0 = (c0A,c1A)|(c2A,c0B); w1 = (c1B,c2B)|(c0C,c1C);
        //        w2 = (c2C,c0D)|(c1D,c2D)
        wrd[3 * k + 0] = enc_pk<true>(pA2[k], pB0[k], enc_pk<false>(pA0[k], pA1[k], 0));
        wrd[3 * k + 1] = enc_pk<true>(pC0[k], pC1[k], enc_pk<false>(pB1[k], pB2[k], 0));
        wrd[3 * k + 2] = enc_pk<true>(pD1[k], pD2[k], enc_pk<false>(pC2[k], pD0[k], 0));
    }
    int t = threadIdx.x;
    #pragma unroll
    for (int j = 0; j < 3; ++j) {
        uint4 v; v.x = wrd[4 * j + 0]; v.y = wrd[4 * j + 1];
        v.z = wrd[4 * j + 2]; v.w = wrd[4 * j + 3];
        sL[t * 3 + j] = v;
    }
    __syncthreads();
    size_t base = (size_t)blockIdx.x * (3 * NTHR);   // uint4 units
    #pragma unroll
    for (int j = 0; j < 3; ++j) {
        int idx = j * NTHR + t;
        P4[base + idx] = sL[idx];
    }
}

// ---------- main: persistent, 4 tiles of (64d x 2h x 8w) per block ----------
__global__ __launch_bounds__(NTHR, 8)
void icl_main(const char* __restrict__ P,
              const float* __restrict__ F, const float* __restrict__ G,
              float* __restrict__ partial) {
    // LDS: apply tile [c(3)][h(2)][w(8)][d(64)] fp32, row-rotated. 12 KB.
    __shared__ float sA[3072];

    int orig = blockIdx.x;             // 0..2047
    int xcd = orig & 7;
    int sbase = orig >> 3;             // 0..255 within XCD
    int dt = xcd & 1, b = (xcd >> 1) & 1, dir = xcd >> 2;

    const float* Ab = (dir ? G : F) + b * BS;          // apply field (planar)
    // dir=0 samples G (field 1); dir=1 samples F (field 0)
    const char* Vbc = P + (size_t)((dir ? 0 : 2) + b) * ((size_t)EB * CS);
    int d0 = dt << 6;

    int t = threadIdx.x;
    int lane = t & 63, wv = t >> 6;
    int h_l = wv & 1, wseg = wv >> 1;
    int d = d0 + lane;
    float acc = 0.0f;

    for (int tt = 0; tt < 4; ++tt) {
        // tile id within XCD plane: 8x8 (ht,wt) super-tiles
        int sid = (tt << 8) | sbase;   // 0..1023
        int u = sid & 63, tile = sid >> 6;
        int ht = ((tile & 7) << 3) | (u & 7);
        int wt = ((tile >> 3) << 3) | (u >> 3);
        int h0 = ht << 1, w0 = wt << 3;
        int h = h0 + h_l;

        if (tt) __syncthreads();       // prior tile's sA reads complete

        // ---- stage apply tile: 3 x (64d x 2h x 8w) floats ----
        #pragma unroll
        for (int j = 0; j < 3; ++j) {
            int rem = t << 2;              // 0..1023
            int d_l = rem >> 4, hh = (rem >> 3) & 1, w_l = rem & 7;
            const float4 v = *(const float4*)(Ab + j * CS + ((d0 + d_l) << 14)
                                              + ((h0 + hh) << 7) + w0 + w_l);
            int Rb = (j * 2 + hh) * 8 + w_l;
            sA[((Rb + 0) << 6) | ((d_l + Rb + 0) & 63)] = v.x;
            sA[((Rb + 1) << 6) | ((d_l + Rb + 1) & 63)] = v.y;
            sA[((Rb + 2) << 6) | ((d_l + Rb + 2) & 63)] = v.z;
            sA[((Rb + 3) << 6) | ((d_l + Rb + 3) & 63)] = v.w;
        }
        __syncthreads();

        // ---- phase 1: coords + weights; issue loads ----
        float A0[4], A1[4], A2[4], WX[4], WY[4], WZ[4];
        int OFF[4];
        #pragma unroll
        for (int i = 0; i < 4; ++i) {
            int w_l = (wseg << 2) | i;
            int w = w0 + w_l;
            int R0 = h_l * 8 + w_l, R1 = 16 + R0, R2 = 32 + R0;
            float a0 = sA[(R0 << 6) | ((lane + R0) & 63)];
            float a1 = sA[(R1 << 6) | ((lane + R1) & 63)];
            float a2 = sA[(R2 << 6) | ((lane + R2) & 63)];
            float fx = fminf(fmaxf((float)d + a0, 0.0f), 127.0f);
            float fy = fminf(fmaxf((float)h + a1, 0.0f), 127.0f);
            float fz = fminf(fmaxf((float)w + a2, 0.0f), 127.0f);
            int x0 = (int)fx, y0 = (int)fy, z0 = (int)fz;
            int x0c = min(x0, 126);
            A0[i] = a0; A1[i] = a1; A2[i] = a2;
            WX[i] = fx - (float)x0c;       // ==1 at fx==127 (exact)
            WY[i] = fy - (float)y0;
            WZ[i] = fz - (float)z0;
            OFF[i] = ((((z0 << 7) | y0) << 7) + x0c) * EB;
        }
        U4a4 QA[4]; U2a4 QB[4];
        #pragma unroll
        for (int i = 0; i < 4; ++i) {
            QA[i] = *(const U4a4*)(Vbc + OFF[i]);       // entry0 + entry1.w0
            QB[i] = *(const U2a4*)(Vbc + OFF[i] + 16);  // entry1.w1, entry1.w2
        }

        // ---- phase 2: decode + packed lerps + accumulate ----
        #pragma unroll
        for (int i = 0; i < 4; ++i) {
            v2f wx2; wx2.x = WX[i]; wx2.y = WX[i];
            v2f wz2; wz2.x = WZ[i]; wz2.y = WZ[i];
            float wy = WY[i];
            v2f p0 = dec_pk<false>(QA[i].x), p1 = dec_pk<true>(QA[i].x);
            v2f p2 = dec_pk<false>(QA[i].y), p3 = dec_pk<true>(QA[i].y);
            v2f p4 = dec_pk<false>(QA[i].z), p5 = dec_pk<true>(QA[i].z);
            v2f q0 = dec_pk<false>(QA[i].w), q1 = dec_pk<true>(QA[i].w);
            v2f q2 = dec_pk<false>(QB[i].x), q3 = dec_pk<true>(QB[i].x);
            v2f q4 = dec_pk<false>(QB[i].y), q5 = dec_pk<true>(QB[i].y);
            v2f X0 = p0 + wx2 * (q0 - p0);
            v2f X1 = p1 + wx2 * (q1 - p1);
            v2f X2 = p2 + wx2 * (q2 - p2);
            v2f X3 = p3 + wx2 * (q3 - p3);
            v2f X4 = p4 + wx2 * (q4 - p4);
            v2f X5 = p5 + wx2 * (q5 - p5);
            v2f Z0 = X0 + wz2 * (X3 - X0);   // (c0@y0, c1@y0)
            v2f Z1 = X1 + wz2 * (X4 - X1);   // (c2@y0, c0@y1)
            v2f Z2 = X2 + wz2 * (X5 - X2);   // (c1@y1, c2@y1)
            float e0 = A0[i] + (Z0.x + wy * (Z1.y - Z0.x));
            float e1 = A1[i] + (Z0.y + wy * (Z2.x - Z0.y));
            float e2 = A2[i] + (Z1.x + wy * (Z2.y - Z1.x));
            acc += e0 * e0 + e1 * e1 + e2 * e2;
        }
    }

    // ---- block reduce ----
    #pragma unroll
    for (int o = 32; o > 0; o >>= 1) acc += __shfl_down(acc, o);
    __shared__ float ws[NTHR / 64];
    if ((t & 63) == 0) ws[t >> 6] = acc;
    __syncthreads();
    if (t == 0) {
        float ssum = 0.0f;
        #pragma unroll
        for (int i = 0; i < NTHR / 64; ++i) ssum += ws[i];
        partial[orig] = ssum;
    }
}

// ---------------- fallback (round-3 path, small ws) ----------------
__device__ __forceinline__ float tri_fb(const float* __restrict__ v,
                                        int zy00, int zy01, int zy10, int zy11,
                                        int x0, int x1,
                                        float wz, float wy, float wx) {
    float c000 = v[zy00 + x0], c001 = v[zy00 + x1];
    float c010 = v[zy01 + x0], c011 = v[zy01 + x1];
    float c100 = v[zy10 + x0], c101 = v[zy10 + x1];
    float c110 = v[zy11 + x0], c111 = v[zy11 + x1];
    float c00 = c000 + wx * (c001 - c000);
    float c01 = c010 + wx * (c011 - c010);
    float c10 = c100 + wx * (c101 - c100);
    float c11 = c110 + wx * (c111 - c110);
    float c0  = c00  + wy * (c01  - c00);
    float c1  = c10  + wy * (c11  - c10);
    return c0 + wz * (c1 - c0);
}

__global__ __launch_bounds__(NTHR, 6)
void icl_partial_fb(const float* __restrict__ F, const float* __restrict__ G,
                    float* __restrict__ partial) {
    __shared__ float sA[6144];
    int orig = blockIdx.x;
    int id = ((orig & 7) << 9) | (orig >> 3);
    int wt  = id & 15;
    int ht  = (id >> 4) & 31;
    int dt  = (id >> 9) & 1;
    int b   = (id >> 10) & 1;
    int dir = id >> 11;
    const float* Ab = (dir ? G : F) + b * BS;
    const float* Vb = (dir ? F : G) + b * BS;
    int d0 = dt << 6, h0 = ht << 2, w0 = wt << 3;
    int t = threadIdx.x;
    #pragma unroll
    for (int j = 0; j < 6; ++j) {
        int L   = (j << 10) + (t << 2);
        int c   = L >> 11;
        int rem = L & 2047;
        int row = rem >> 3;
        int w_l = rem & 7;
        int d_l = row >> 2, h_l = row & 3;
        const float4 v = *(const float4*)(Ab + c * CS + ((d0 + d_l) << 14)
                                          + ((h0 + h_l) << 7) + w0 + w_l);
        int Rb = (c * 4 + h_l) * 8 + w_l;
        sA[((Rb + 0) << 6) | ((d_l + Rb + 0) & 63)] = v.x;
        sA[((Rb + 1) << 6) | ((d_l + Rb + 1) & 63)] = v.y;
        sA[((Rb + 2) << 6) | ((d_l + Rb + 2) & 63)] = v.z;
        sA[((Rb + 3) << 6) | ((d_l + Rb + 3) & 63)] = v.w;
    }
    __syncthreads();
    int lane = t & 63, wv = t >> 6;
    int d = d0 + lane;
    float acc = 0.0f;
    #pragma unroll 4
    for (int i = 0; i < 8; ++i) {
        int h = h0 + wv, w = w0 + i;
        int R0 = (0 * 4 + wv) * 8 + i;
        int R1 = (1 * 4 + wv) * 8 + i;
        int R2 = (2 * 4 + wv) * 8 + i;
        float a0 = sA[(R0 << 6) | ((lane + R0) & 63)];
        float a1 = sA[(R1 << 6) | ((lane + R1) & 63)];
        float a2 = sA[(R2 << 6) | ((lane + R2) & 63)];
        float fx = fminf(fmaxf((float)d + a0, 0.0f), 127.0f);
        float fy = fminf(fmaxf((float)h + a1, 0.0f), 127.0f);
        float fz = fminf(fmaxf((float)w + a2, 0.0f), 127.0f);
        int x0 = (int)fx, y0 = (int)fy, z0 = (int)fz;
        float wx = fx - (float)x0, wy = fy - (float)y0, wz = fz - (float)z0;
        int x1 = min(x0 + 1, 127), y1 = min(y0 + 1, 127), z1 = min(z0 + 1, 127);
        int zy00 = ((z0 << 7) | y0) << 7;
        int zy01 = ((z0 << 7) | y1) << 7;
        int zy10 = ((z1 << 7) | y0) << 7;
        int zy11 = ((z1 << 7) | y1) << 7;
        float s0 = tri_fb(Vb,        zy00, zy01, zy10, zy11, x0, x1, wz, wy, wx);
        float s1 = tri_fb(Vb + CS,   zy00, zy01, zy10, zy11, x0, x1, wz, wy, wx);
        float s2 = tri_fb(Vb + 2*CS, zy00, zy01, zy10, zy11, x0, x1, wz, wy, wx);
        float e0 = a0 + s0, e1 = a1 + s1, e2 = a2 + s2;
        acc += e0 * e0 + e1 * e1 + e2 * e2;
    }
    #pragma unroll
    for (int o = 32; o > 0; o >>= 1) acc += __shfl_down(acc, o);
    __shared__ float ws[NTHR / 64];
    if ((t & 63) == 0) ws[t >> 6] = acc;
    __syncthreads();
    if (t == 0) {
        float s = 0.0f;
        #pragma unroll
        for (int i = 0; i < NTHR / 64; ++i) s += ws[i];
        partial[orig] = s;
    }
}

__global__ __launch_bounds__(NTHR)
void icl_final(const float* __restrict__ partial, float* __restrict__ out, int n) {
    float a = 0.0f;
    for (int i = threadIdx.x; i < n; i += NTHR) a += partial[i];
    #pragma unroll
    for (int o = 32; o > 0; o >>= 1) a += __shfl_down(a, o);
    __shared__ float ws[NTHR / 64];
    if ((threadIdx.x & 63) == 0) ws[threadIdx.x >> 6] = a;
    __syncthreads();
    if (threadIdx.x == 0) {
        float s = 0.0f;
        #pragma unroll
        for (int i = 0; i < NTHR / 64; ++i) s += ws[i];
        out[0] = s * INV_N;
    }
}

extern "C" void kernel_launch(void* const* d_in, const int* in_sizes, int n_in,
                              void* d_out, int out_size, void* d_ws, size_t ws_size,
                              hipStream_t stream) {
    const float* F = (const float*)d_in[0];   // dvf_fwd
    const float* G = (const float*)d_in[1];   // dvf_bwd
    size_t packed_bytes = (size_t)4 * EB * CS;   // 100.7 MB total
    size_t need = packed_bytes + NBLK_MAIN * sizeof(float) + 256;
    if (ws_size >= need) {
        char* P = (char*)d_ws;
        float* partial = (float*)(P + packed_bytes);
        repack12<<<8192, NTHR, 0, stream>>>(F, G, (uint4*)P);
        icl_main<<<NBLK_MAIN, NTHR, 0, stream>>>(P, F, G, partial);
        icl_final<<<1, NTHR, 0, stream>>>(partial, (float*)d_out, NBLK_MAIN);
    } else {
        float* partial = (float*)d_ws;
        icl_partial_fb<<<4096, NTHR, 0, stream>>>(F, G, partial);
        icl_final<<<1, NTHR, 0, stream>>>(partial, (float*)d_out, 4096);
    }
}

// Round 13
// 99.010 us; speedup vs baseline: 1.7322x; 1.7322x over previous
//
#include <hip/hip_runtime.h>

// InverseConsistencyLoss — round 13: revert to r11's proven 8192-block main
// (r12's persistent schedule thrashed L2: FETCH 104->232MB), v3 repack
// (float4 reads, LDS-staged dense stores), and PIPELINE the stages:
//   k1: repack field G
//   k2: fused {repack field F (blocks 0..4095) || main dir0 (4096..8191)}
//       - main0 reads packed-G (ready after k1); repack-F output only read by k3
//   k3: main dir1   k4: final reduce
// Entry(z,y,x) = {c0,c1,c2} at (z,y),(z,y1),(z1,y),(z1,y1), clamps baked, 12B.
// Main: dwordx4+dwordx2 at byte 12*idx span 24 contiguous bytes = all 8
// trilinear corners. Packed v2f lerps. Sample semantics: output voxel (d,h,w)
// samples V at (z=clip(w+a2), y=clip(h+a1), x=clip(d+a0)), x fastest; lane==d.

#define CS    2097152          // 128^3
#define BS    (3*CS)
#define NTHR  256
#define EB    12               // entry bytes
#define U4_PER_FIELD 3145728   // 2^22 entries * 12B / 16B
#define INV_N (1.0f/12582912.0f)

#if defined(__has_builtin)
#if __has_builtin(__builtin_amdgcn_cvt_pk_fp8_f32) && __has_builtin(__builtin_amdgcn_cvt_pk_f32_fp8)
#define HW_FP8 1
#endif
#endif

typedef float v2f __attribute__((ext_vector_type(2)));
struct __attribute__((aligned(4))) U4a4 { unsigned x, y, z, w; };
struct __attribute__((aligned(4))) U2a4 { unsigned x, y; };

// ---------- OCP e4m3fn helpers ----------
__device__ __forceinline__ unsigned enc1_sw(float x) {
    union { float f; unsigned u; } v; v.f = x;
    unsigned s = v.u >> 31;
    float ax = fminf(fabsf(x), 448.0f);
    if (ax < 0.015625f) return s << 7;
    v.f = ax;
    unsigned u = v.u;
    u += 0x7FFFF + ((u >> 20) & 1);
    unsigned e = (u >> 23) - 120;
    if (e > 15) { e = 15; u = 0x7u << 20; }
    return (s << 7) | (e << 3) | ((u >> 20) & 7);
}
__device__ __forceinline__ float dec1_sw(unsigned b) {
    unsigned s = b >> 7, e = (b >> 3) & 15, m = b & 7;
    union { unsigned u; float f; } v;
    if (e == 0) { float r = (float)m * 0.001953125f; return s ? -r : r; }
    v.u = (s << 31) | ((e + 120) << 23) | (m << 20);
    return v.f;
}
template <bool HI>
__device__ __forceinline__ unsigned enc_pk(float a, float b, unsigned old) {
#ifdef HW_FP8
    return (unsigned)__builtin_amdgcn_cvt_pk_fp8_f32(a, b, (int)old, HI);
#else
    unsigned p = enc1_sw(a) | (enc1_sw(b) << 8);
    return HI ? ((old & 0x0000FFFFu) | (p << 16)) : ((old & 0xFFFF0000u) | p);
#endif
}
template <bool HI>
__device__ __forceinline__ v2f dec_pk(unsigned u) {
#ifdef HW_FP8
    return __builtin_amdgcn_cvt_pk_f32_fp8((int)u, HI);
#else
    unsigned p = HI ? (u >> 16) : u;
    v2f r; r.x = dec1_sw(p & 255); r.y = dec1_sw((p >> 8) & 255);
    return r;
#endif
}

// ---------- repack body: 4 entries/thread, float4 reads, dense stores -------
// one field = 2^20 threads = 4096 blocks. bid local to this field.
__device__ __forceinline__ void repack_body(const float* __restrict__ src0,
                                            uint4* __restrict__ P4,
                                            int field, int bid, int t,
                                            uint4* __restrict__ sL) {
    unsigned g = (unsigned)bid * NTHR + t;   // 0 .. 2^20-1
    int x = (g & 31) << 2;
    int y = (g >> 5) & 127;
    int z = (g >> 12) & 127;
    int b = (g >> 19) & 1;
    const float* src = src0 + b * BS;
    int y1 = min(y + 1, 127), z1 = min(z + 1, 127);
    int iA = (z << 14) + (y << 7) + x;
    int iB = (z << 14) + (y1 << 7) + x;
    int iC = (z1 << 14) + (y << 7) + x;
    int iD = (z1 << 14) + (y1 << 7) + x;
    float4 A0 = *(const float4*)(src + iA);
    float4 A1 = *(const float4*)(src + CS + iA);
    float4 A2 = *(const float4*)(src + 2 * CS + iA);
    float4 B0 = *(const float4*)(src + iB);
    float4 B1 = *(const float4*)(src + CS + iB);
    float4 B2 = *(const float4*)(src + 2 * CS + iB);
    float4 C0 = *(const float4*)(src + iC);
    float4 C1 = *(const float4*)(src + CS + iC);
    float4 C2 = *(const float4*)(src + 2 * CS + iC);
    float4 D0 = *(const float4*)(src + iD);
    float4 D1 = *(const float4*)(src + CS + iD);
    float4 D2 = *(const float4*)(src + 2 * CS + iD);
    const float* pA0 = (const float*)&A0; const float* pA1 = (const float*)&A1;
    const float* pA2 = (const float*)&A2; const float* pB0 = (const float*)&B0;
    const float* pB1 = (const float*)&B1; const float* pB2 = (const float*)&B2;
    const float* pC0 = (const float*)&C0; const float* pC1 = (const float*)&C1;
    const float* pC2 = (const float*)&C2; const float* pD0 = (const float*)&D0;
    const float* pD1 = (const float*)&D1; const float* pD2 = (const float*)&D2;
    unsigned wrd[12];
    #pragma unroll
    for (int k = 0; k < 4; ++k) {
        wrd[3 * k + 0] = enc_pk<true>(pA2[k], pB0[k], enc_pk<false>(pA0[k], pA1[k], 0));
        wrd[3 * k + 1] = enc_pk<true>(pC0[k], pC1[k], enc_pk<false>(pB1[k], pB2[k], 0));
        wrd[3 * k + 2] = enc_pk<true>(pD1[k], pD2[k], enc_pk<false>(pC2[k], pD0[k], 0));
    }
    #pragma unroll
    for (int j = 0; j < 3; ++j) {
        uint4 v; v.x = wrd[4 * j + 0]; v.y = wrd[4 * j + 1];
        v.z = wrd[4 * j + 2]; v.w = wrd[4 * j + 3];
        sL[t * 3 + j] = v;
    }
    __syncthreads();
    size_t base = (size_t)field * U4_PER_FIELD + (size_t)bid * (3 * NTHR);
    #pragma unroll
    for (int j = 0; j < 3; ++j) {
        int idx = j * NTHR + t;
        P4[base + idx] = sL[idx];
    }
}

// ---------- main body: one direction, 4096 blocks, tile (64d x 2h x 8w) -----
// xcd owns (b, dt, ht-half); 8x8 supertiles within.
__device__ __forceinline__ void main_body(const char* __restrict__ P,
                                          const float* __restrict__ A,
                                          int sf, int orig, int t,
                                          float* __restrict__ sA,
                                          float* __restrict__ partial_slot) {
    int xcd = orig & 7;
    int idx = orig >> 3;               // 0..511
    int dt = xcd & 1, b = (xcd >> 1) & 1, half = xcd >> 2;
    int u = idx & 63, st = idx >> 6;   // st 0..7
    int ht = (half << 5) | ((st & 3) << 3) | (u & 7);   // 0..63
    int wt = ((st >> 2) << 3) | (u >> 3);               // 0..15
    const float* Ab = A + b * BS;
    const char* Vbc = P + (size_t)(sf * 2 + b) * ((size_t)EB * CS);
    int d0 = dt << 6, h0 = ht << 1, w0 = wt << 3;

    // stage apply tile: 3 x (64d x 2h x 8w) floats, row-rotated
    #pragma unroll
    for (int j = 0; j < 3; ++j) {
        int rem = t << 2;
        int d_l = rem >> 4, hh = (rem >> 3) & 1, w_l = rem & 7;
        const float4 v = *(const float4*)(Ab + j * CS + ((d0 + d_l) << 14)
                                          + ((h0 + hh) << 7) + w0 + w_l);
        int Rb = (j * 2 + hh) * 8 + w_l;
        sA[((Rb + 0) << 6) | ((d_l + Rb + 0) & 63)] = v.x;
        sA[((Rb + 1) << 6) | ((d_l + Rb + 1) & 63)] = v.y;
        sA[((Rb + 2) << 6) | ((d_l + Rb + 2) & 63)] = v.z;
        sA[((Rb + 3) << 6) | ((d_l + Rb + 3) & 63)] = v.w;
    }
    __syncthreads();

    int lane = t & 63, wv = t >> 6;
    int h_l = wv & 1, wseg = wv >> 1;
    int d = d0 + lane, h = h0 + h_l;

    float A0[4], A1[4], A2[4], WX[4], WY[4], WZ[4];
    int OFF[4];
    #pragma unroll
    for (int i = 0; i < 4; ++i) {
        int w_l = (wseg << 2) | i;
        int w = w0 + w_l;
        int R0 = h_l * 8 + w_l, R1 = 16 + R0, R2 = 32 + R0;
        float a0 = sA[(R0 << 6) | ((lane + R0) & 63)];
        float a1 = sA[(R1 << 6) | ((lane + R1) & 63)];
        float a2 = sA[(R2 << 6) | ((lane + R2) & 63)];
        float fx = fminf(fmaxf((float)d + a0, 0.0f), 127.0f);
        float fy = fminf(fmaxf((float)h + a1, 0.0f), 127.0f);
        float fz = fminf(fmaxf((float)w + a2, 0.0f), 127.0f);
        int x0 = (int)fx, y0 = (int)fy, z0 = (int)fz;
        int x0c = min(x0, 126);
        A0[i] = a0; A1[i] = a1; A2[i] = a2;
        WX[i] = fx - (float)x0c;
        WY[i] = fy - (float)y0;
        WZ[i] = fz - (float)z0;
        OFF[i] = ((((z0 << 7) | y0) << 7) + x0c) * EB;
    }
    U4a4 QA[4]; U2a4 QB[4];
    #pragma unroll
    for (int i = 0; i < 4; ++i) {
        QA[i] = *(const U4a4*)(Vbc + OFF[i]);
        QB[i] = *(const U2a4*)(Vbc + OFF[i] + 16);
    }

    float acc = 0.0f;
    #pragma unroll
    for (int i = 0; i < 4; ++i) {
        v2f wx2; wx2.x = WX[i]; wx2.y = WX[i];
        v2f wz2; wz2.x = WZ[i]; wz2.y = WZ[i];
        float wy = WY[i];
        v2f p0 = dec_pk<false>(QA[i].x), p1 = dec_pk<true>(QA[i].x);
        v2f p2 = dec_pk<false>(QA[i].y), p3 = dec_pk<true>(QA[i].y);
        v2f p4 = dec_pk<false>(QA[i].z), p5 = dec_pk<true>(QA[i].z);
        v2f q0 = dec_pk<false>(QA[i].w), q1 = dec_pk<true>(QA[i].w);
        v2f q2 = dec_pk<false>(QB[i].x), q3 = dec_pk<true>(QB[i].x);
        v2f q4 = dec_pk<false>(QB[i].y), q5 = dec_pk<true>(QB[i].y);
        v2f X0 = p0 + wx2 * (q0 - p0);
        v2f X1 = p1 + wx2 * (q1 - p1);
        v2f X2 = p2 + wx2 * (q2 - p2);
        v2f X3 = p3 + wx2 * (q3 - p3);
        v2f X4 = p4 + wx2 * (q4 - p4);
        v2f X5 = p5 + wx2 * (q5 - p5);
        v2f Z0 = X0 + wz2 * (X3 - X0);   // (c0@y0, c1@y0)
        v2f Z1 = X1 + wz2 * (X4 - X1);   // (c2@y0, c0@y1)
        v2f Z2 = X2 + wz2 * (X5 - X2);   // (c1@y1, c2@y1)
        float e0 = A0[i] + (Z0.x + wy * (Z1.y - Z0.x));
        float e1 = A1[i] + (Z0.y + wy * (Z2.x - Z0.y));
        float e2 = A2[i] + (Z1.x + wy * (Z2.y - Z1.x));
        acc += e0 * e0 + e1 * e1 + e2 * e2;
    }

    #pragma unroll
    for (int o = 32; o > 0; o >>= 1) acc += __shfl_down(acc, o);
    __shared__ float wsum[NTHR / 64];
    if ((t & 63) == 0) wsum[t >> 6] = acc;
    __syncthreads();
    if (t == 0) {
        float ssum = 0.0f;
        #pragma unroll
        for (int i = 0; i < NTHR / 64; ++i) ssum += wsum[i];
        *partial_slot = ssum;
    }
}

// ---------- kernels ----------
__global__ __launch_bounds__(NTHR)
void k_repack(const float* __restrict__ F, const float* __restrict__ G,
              uint4* __restrict__ P4, int field) {
    __shared__ uint4 sL[3 * NTHR];
    repack_body(field ? G : F, P4, field, blockIdx.x, threadIdx.x, sL);
}

__global__ __launch_bounds__(NTHR, 8)
void k_fused(const float* __restrict__ F, const float* __restrict__ G,
             uint4* __restrict__ P4, float* __restrict__ partial) {
    __shared__ char smem[12288];
    int bid = blockIdx.x, t = threadIdx.x;
    if (bid < 4096) {
        // repack field 0 (F)
        repack_body(F, P4, 0, bid, t, (uint4*)smem);
    } else {
        // main dir0: apply F, sample field 1 (G)
        main_body((const char*)P4, F, 1, bid - 4096, t, (float*)smem,
                  partial + (bid - 4096));
    }
}

__global__ __launch_bounds__(NTHR, 8)
void k_main1(const float* __restrict__ G, uint4* __restrict__ P4,
             float* __restrict__ partial) {
    __shared__ float sA[3072];
    // main dir1: apply G, sample field 0 (F)
    main_body((const char*)P4, G, 0, blockIdx.x, threadIdx.x, sA,
              partial + 4096 + blockIdx.x);
}

__global__ __launch_bounds__(NTHR)
void icl_final(const float* __restrict__ partial, float* __restrict__ out, int n) {
    float a = 0.0f;
    for (int i = threadIdx.x; i < n; i += NTHR) a += partial[i];
    #pragma unroll
    for (int o = 32; o > 0; o >>= 1) a += __shfl_down(a, o);
    __shared__ float ws[NTHR / 64];
    if ((threadIdx.x & 63) == 0) ws[threadIdx.x >> 6] = a;
    __syncthreads();
    if (threadIdx.x == 0) {
        float s = 0.0f;
        #pragma unroll
        for (int i = 0; i < NTHR / 64; ++i) s += ws[i];
        out[0] = s * INV_N;
    }
}

// ---------------- fallback (round-3 path, small ws) ----------------
__device__ __forceinline__ float tri_fb(const float* __restrict__ v,
                                        int zy00, int zy01, int zy10, int zy11,
                                        int x0, int x1,
                                        float wz, float wy, float wx) {
    float c000 = v[zy00 + x0], c001 = v[zy00 + x1];
    float c010 = v[zy01 + x0], c011 = v[zy01 + x1];
    float c100 = v[zy10 + x0], c101 = v[zy10 + x1];
    float c110 = v[zy11 + x0], c111 = v[zy11 + x1];
    float c00 = c000 + wx * (c001 - c000);
    float c01 = c010 + wx * (c011 - c010);
    float c10 = c100 + wx * (c101 - c100);
    float c11 = c110 + wx * (c111 - c110);
    float c0  = c00  + wy * (c01  - c00);
    float c1  = c10  + wy * (c11  - c10);
    return c0 + wz * (c1 - c0);
}

__global__ __launch_bounds__(NTHR, 6)
void icl_partial_fb(const float* __restrict__ F, const float* __restrict__ G,
                    float* __restrict__ partial) {
    __shared__ float sA[6144];
    int orig = blockIdx.x;
    int id = ((orig & 7) << 9) | (orig >> 3);
    int wt  = id & 15;
    int ht  = (id >> 4) & 31;
    int dt  = (id >> 9) & 1;
    int b   = (id >> 10) & 1;
    int dir = id >> 11;
    const float* Ab = (dir ? G : F) + b * BS;
    const float* Vb = (dir ? F : G) + b * BS;
    int d0 = dt << 6, h0 = ht << 2, w0 = wt << 3;
    int t = threadIdx.x;
    #pragma unroll
    for (int j = 0; j < 6; ++j) {
        int L   = (j << 10) + (t << 2);
        int c   = L >> 11;
        int rem = L & 2047;
        int row = rem >> 3;
        int w_l = rem & 7;
        int d_l = row >> 2, h_l = row & 3;
        const float4 v = *(const float4*)(Ab + c * CS + ((d0 + d_l) << 14)
                                          + ((h0 + h_l) << 7) + w0 + w_l);
        int Rb = (c * 4 + h_l) * 8 + w_l;
        sA[((Rb + 0) << 6) | ((d_l + Rb + 0) & 63)] = v.x;
        sA[((Rb + 1) << 6) | ((d_l + Rb + 1) & 63)] = v.y;
        sA[((Rb + 2) << 6) | ((d_l + Rb + 2) & 63)] = v.z;
        sA[((Rb + 3) << 6) | ((d_l + Rb + 3) & 63)] = v.w;
    }
    __syncthreads();
    int lane = t & 63, wv = t >> 6;
    int d = d0 + lane;
    float acc = 0.0f;
    #pragma unroll 4
    for (int i = 0; i < 8; ++i) {
        int h = h0 + wv, w = w0 + i;
        int R0 = (0 * 4 + wv) * 8 + i;
        int R1 = (1 * 4 + wv) * 8 + i;
        int R2 = (2 * 4 + wv) * 8 + i;
        float a0 = sA[(R0 << 6) | ((lane + R0) & 63)];
        float a1 = sA[(R1 << 6) | ((lane + R1) & 63)];
        float a2 = sA[(R2 << 6) | ((lane + R2) & 63)];
        float fx = fminf(fmaxf((float)d + a0, 0.0f), 127.0f);
        float fy = fminf(fmaxf((float)h + a1, 0.0f), 127.0f);
        float fz = fminf(fmaxf((float)w + a2, 0.0f), 127.0f);
        int x0 = (int)fx, y0 = (int)fy, z0 = (int)fz;
        float wx = fx - (float)x0, wy = fy - (float)y0, wz = fz - (float)z0;
        int x1 = min(x0 + 1, 127), y1 = min(y0 + 1, 127), z1 = min(z0 + 1, 127);
        int zy00 = ((z0 << 7) | y0) << 7;
        int zy01 = ((z0 << 7) | y1) << 7;
        int zy10 = ((z1 << 7) | y0) << 7;
        int zy11 = ((z1 << 7) | y1) << 7;
        float s0 = tri_fb(Vb,        zy00, zy01, zy10, zy11, x0, x1, wz, wy, wx);
        float s1 = tri_fb(Vb + CS,   zy00, zy01, zy10, zy11, x0, x1, wz, wy, wx);
        float s2 = tri_fb(Vb + 2*CS, zy00, zy01, zy10, zy11, x0, x1, wz, wy, wx);
        float e0 = a0 + s0, e1 = a1 + s1, e2 = a2 + s2;
        acc += e0 * e0 + e1 * e1 + e2 * e2;
    }
    #pragma unroll
    for (int o = 32; o > 0; o >>= 1) acc += __shfl_down(acc, o);
    __shared__ float ws[NTHR / 64];
    if ((t & 63) == 0) ws[t >> 6] = acc;
    __syncthreads();
    if (t == 0) {
        float s = 0.0f;
        #pragma unroll
        for (int i = 0; i < NTHR / 64; ++i) s += ws[i];
        partial[orig] = s;
    }
}

extern "C" void kernel_launch(void* const* d_in, const int* in_sizes, int n_in,
                              void* d_out, int out_size, void* d_ws, size_t ws_size,
                              hipStream_t stream) {
    const float* F = (const float*)d_in[0];   // dvf_fwd
    const float* G = (const float*)d_in[1];   // dvf_bwd
    size_t packed_bytes = (size_t)4 * EB * CS;   // 100.7 MB total
    size_t need = packed_bytes + 8192 * sizeof(float) + 256;
    if (ws_size >= need) {
        uint4* P4 = (uint4*)d_ws;
        float* partial = (float*)((char*)d_ws + packed_bytes);
        k_repack<<<4096, NTHR, 0, stream>>>(F, G, P4, 1);          // pack G
        k_fused<<<8192, NTHR, 0, stream>>>(F, G, P4, partial);     // pack F || main0
        k_main1<<<4096, NTHR, 0, stream>>>(G, P4, partial);        // main1
        icl_final<<<1, NTHR, 0, stream>>>(partial, (float*)d_out, 8192);
    } else {
        float* partial = (float*)d_ws;
        icl_partial_fb<<<4096, NTHR, 0, stream>>>(F, G, partial);
        icl_final<<<1, NTHR, 0, stream>>>(partial, (float*)d_out, 4096);
    }
}